// Round 5
// baseline (159.209 us; speedup 1.0000x reference)
//
#include <hip/hip_runtime.h>
#include <hip/hip_bf16.h>

#define BB 4
#define NN 4096
#define DIN 512
#define DD 64

typedef __attribute__((ext_vector_type(8))) short short8;
typedef __attribute__((ext_vector_type(4))) float f32x4;
typedef __attribute__((ext_vector_type(4))) unsigned short us4;
using bf16 = __hip_bfloat16;

__device__ inline void mfma_16x16x32(f32x4& d, short8 a, short8 b) {
    asm("v_mfma_f32_16x16x32_bf16 %0, %1, %2, %0" : "+v"(d) : "v"(a), "v"(b));
}

__device__ inline short8 load_cvt8(const float* __restrict__ src) {
    f32x4 f0 = *(const f32x4*)(src);
    f32x4 f1 = *(const f32x4*)(src + 4);
    bf16 t[8];
    #pragma unroll
    for (int j = 0; j < 4; ++j) t[j]     = __float2bfloat16(f0[j]);
    #pragma unroll
    for (int j = 0; j < 4; ++j) t[4 + j] = __float2bfloat16(f1[j]);
    return *(short8*)t;
}

// ---------------- W transpose+convert: WT[g][kk] = W_{g/64}[kk][g%64] -----
__global__ __launch_bounds__(256) void convw_kernel(
    const float* __restrict__ Wq, const float* __restrict__ Wk,
    const float* __restrict__ Wv, bf16* __restrict__ WT)
{
    int idx = blockIdx.x * 256 + threadIdx.x;   // 3*64*512 = 98304
    int w   = idx >> 15;
    int rem = idx & 32767;
    int n   = rem >> 9;
    int kk  = rem & 511;
    const float* W = (w == 0) ? Wq : (w == 1) ? Wk : Wv;
    WT[idx] = __float2bfloat16(W[kk * DD + n]);
}

// ---------------- MFMA projection, A direct from global -------------------
__global__ __launch_bounds__(512) void proj_kernel(
    const float* __restrict__ x, const bf16* __restrict__ WT,
    bf16* __restrict__ q, bf16* __restrict__ k, bf16* __restrict__ vT)
{
    const int tid   = threadIdx.x;
    const int row0  = blockIdx.x * 64;
    const int b     = row0 >> 12;
    const int nrow0 = row0 & 4095;
    const int lane  = tid & 63;
    const int l16   = lane & 15;
    const int lg    = lane >> 4;
    const int wave  = tid >> 6;
    const int rblk  = (wave >> 2) * 32;
    const int cbase = (wave & 3) * 48;

    f32x4 acc[2][3];
    #pragma unroll
    for (int rt = 0; rt < 2; ++rt)
        #pragma unroll
        for (int ct = 0; ct < 3; ++ct) acc[rt][ct] = (f32x4){0.f, 0.f, 0.f, 0.f};

    const float* xa = x  + (size_t)(row0 + rblk + l16) * DIN + lg * 8;
    const bf16*  wb = WT + (size_t)(cbase + l16) * DIN + lg * 8;

    #pragma unroll 4
    for (int ks = 0; ks < 16; ++ks) {
        short8 a0 = load_cvt8(xa + ks * 32);
        short8 a1 = load_cvt8(xa + 16 * DIN + ks * 32);
        short8 w0 = *(const short8*)(wb + ks * 32);
        short8 w1 = *(const short8*)(wb + 16 * DIN + ks * 32);
        short8 w2 = *(const short8*)(wb + 32 * DIN + ks * 32);
        mfma_16x16x32(acc[0][0], a0, w0);
        mfma_16x16x32(acc[0][1], a0, w1);
        mfma_16x16x32(acc[0][2], a0, w2);
        mfma_16x16x32(acc[1][0], a1, w0);
        mfma_16x16x32(acc[1][1], a1, w1);
        mfma_16x16x32(acc[1][2], a1, w2);
    }

    #pragma unroll
    for (int ct = 0; ct < 3; ++ct) {
        int g = cbase + ct * 16 + l16;
        int w = g >> 6;
        int n = g & 63;
        #pragma unroll
        for (int rt = 0; rt < 2; ++rt) {
            if (w == 2) {
                us4 pv;
                #pragma unroll
                for (int r = 0; r < 4; ++r) {
                    bf16 hv = __float2bfloat16(acc[rt][ct][r]);
                    pv[r] = *(unsigned short*)&hv;
                }
                int row = nrow0 + rblk + rt * 16 + lg * 4;
                *(us4*)(vT + ((size_t)b * DD + n) * NN + row) = pv;
            } else {
                bf16* dst = (w == 0) ? q : k;
                float sc  = (w == 0) ? 0.125f : 1.0f;
                #pragma unroll
                for (int r = 0; r < 4; ++r) {
                    int row = nrow0 + rblk + rt * 16 + lg * 4 + r;
                    dst[((size_t)b * NN + row) * DD + n] =
                        __float2bfloat16(acc[rt][ct][r] * sc);
                }
            }
        }
    }
}

// ---------------- split-KV flash attention, 128-key iterations ------------
// work idx -> (b, qt, s); each block: 64 q-rows, tiles of 128 keys
__global__ __launch_bounds__(256) void attn_split_kernel(
    const bf16* __restrict__ q, const bf16* __restrict__ k,
    const bf16* __restrict__ vT,
    float* __restrict__ partO, float* __restrict__ partML,
    float* __restrict__ out, int S)
{
    // XCD-aware swizzle: consecutive work idx -> same XCD (grid % 8 == 0)
    const int cpx = gridDim.x >> 3;
    const int idx = (blockIdx.x & 7) * cpx + (blockIdx.x >> 3);

    const int s   = idx % S;
    const int qt  = (idx / S) & 63;
    const int b   = idx / (S * 64);
    const int T   = (qt + 2) >> 1;          // # of 128-key blocks
    const int len = (T + S - 1) / S;
    const int t0  = s * len;
    const int t1  = (t0 + len < T) ? t0 + len : T;

    if (t0 >= t1) {                          // empty split: neutral partials
        const int tid = threadIdx.x;
        const int row = tid >> 2;
        const int c0  = (tid & 3) << 4;
        f32x4 z = (f32x4){0.f, 0.f, 0.f, 0.f};
        f32x4* po = (f32x4*)(partO + (size_t)idx * 4096 + row * 64 + c0);
        #pragma unroll
        for (int j = 0; j < 4; ++j) po[j] = z;
        if (tid < 64) {
            partML[(size_t)idx * 128 + tid]      = -INFINITY;
            partML[(size_t)idx * 128 + 64 + tid] = 0.f;
        }
        return;
    }

    const int wave = threadIdx.x >> 6;
    const int lane = threadIdx.x & 63;
    const int l16  = lane & 15;
    const int lg   = lane >> 4;

    __shared__ __align__(16) bf16 p_lds[4][16][128];   // 16 KB, XOR-swizzled
    char* pbase_lds = (char*)p_lds + wave * 4096;

    const int row0g = qt * 64 + wave * 16;   // wave's first q row (global)

    const bf16* qbase = q + ((size_t)b * NN + row0g + l16) * DD + lg * 8;
    short8 qfrag0 = *(const short8*)(qbase);
    short8 qfrag1 = *(const short8*)(qbase + 32);

    f32x4 oacc[4];
    #pragma unroll
    for (int dt = 0; dt < 4; ++dt) oacc[dt] = (f32x4){0.f, 0.f, 0.f, 0.f};
    float m[4], l[4];
    #pragma unroll
    for (int r = 0; r < 4; ++r) { m[r] = -INFINITY; l[r] = 0.f; }

    const bf16* kbase0 = k + ((size_t)b * NN + l16) * DD + lg * 8;
    const bf16* vbase0 = vT + ((size_t)b * DD + l16) * NN + lg * 8;

    // prefetch K for first tile
    short8 kf[8][2];
    {
        const bf16* kp = kbase0 + (size_t)t0 * 128 * DD;
        #pragma unroll
        for (int ct = 0; ct < 8; ++ct) {
            kf[ct][0] = *(const short8*)(kp + (size_t)ct * 16 * DD);
            kf[ct][1] = *(const short8*)(kp + (size_t)ct * 16 * DD + 32);
        }
    }

    for (int t = t0; t < t1; ++t) {
        // ---- S = Q K^T over 128 keys ----
        f32x4 sc[8];
        #pragma unroll
        for (int ct = 0; ct < 8; ++ct) sc[ct] = (f32x4){0.f, 0.f, 0.f, 0.f};
        #pragma unroll
        for (int ct = 0; ct < 8; ++ct) {
            mfma_16x16x32(sc[ct], qfrag0, kf[ct][0]);
            mfma_16x16x32(sc[ct], qfrag1, kf[ct][1]);
        }

        // ---- early-issue V loads for this tile ----
        const bf16* vbase = vbase0 + (size_t)t * 128;
        short8 vf[4][4];
        #pragma unroll
        for (int dt = 0; dt < 4; ++dt)
            #pragma unroll
            for (int kc = 0; kc < 4; ++kc)
                vf[dt][kc] = *(const short8*)(vbase + (size_t)dt * 16 * NN + kc * 32);

        // ---- prefetch K for next tile (covered by softmax+PV) ----
        if (t + 1 < t1) {
            const bf16* kp = kbase0 + (size_t)(t + 1) * 128 * DD;
            #pragma unroll
            for (int ct = 0; ct < 8; ++ct) {
                kf[ct][0] = *(const short8*)(kp + (size_t)ct * 16 * DD);
                kf[ct][1] = *(const short8*)(kp + (size_t)ct * 16 * DD + 32);
            }
        }

        // ---- causal mask (only when tile can touch the diagonal) ----
        if (t * 128 + 127 > row0g) {
            #pragma unroll
            for (int ct = 0; ct < 8; ++ct) {
                int gk = t * 128 + ct * 16 + l16;
                #pragma unroll
                for (int r = 0; r < 4; ++r)
                    if (gk > row0g + lg * 4 + r)
                        sc[ct][r] = -INFINITY;
            }
        }

        // ---- online softmax over 128 keys ----
        float mt[4];
        #pragma unroll
        for (int r = 0; r < 4; ++r) {
            float a = fmaxf(fmaxf(sc[0][r], sc[1][r]), fmaxf(sc[2][r], sc[3][r]));
            float c = fmaxf(fmaxf(sc[4][r], sc[5][r]), fmaxf(sc[6][r], sc[7][r]));
            mt[r] = fmaxf(a, c);
        }
        #pragma unroll
        for (int off = 1; off < 16; off <<= 1)
            #pragma unroll
            for (int r = 0; r < 4; ++r)
                mt[r] = fmaxf(mt[r], __shfl_xor(mt[r], off));

        float alpha[4];
        #pragma unroll
        for (int r = 0; r < 4; ++r) {
            float mn = fmaxf(m[r], mt[r]);
            alpha[r] = __expf(m[r] - mn);
            m[r] = mn;
        }

        float ls[4] = {0.f, 0.f, 0.f, 0.f};
        #pragma unroll
        for (int ct = 0; ct < 8; ++ct)
            #pragma unroll
            for (int r = 0; r < 4; ++r) {
                float p = __expf(sc[ct][r] - m[r]);
                sc[ct][r] = p;
                ls[r] += p;
            }
        #pragma unroll
        for (int off = 1; off < 16; off <<= 1)
            #pragma unroll
            for (int r = 0; r < 4; ++r)
                ls[r] += __shfl_xor(ls[r], off);
        #pragma unroll
        for (int r = 0; r < 4; ++r)
            l[r] = l[r] * alpha[r] + ls[r];

        #pragma unroll
        for (int dt = 0; dt < 4; ++dt)
            #pragma unroll
            for (int r = 0; r < 4; ++r)
                oacc[dt][r] *= alpha[r];

        // ---- P -> LDS (XOR-swizzled rows) ----
        #pragma unroll
        for (int ct = 0; ct < 8; ++ct)
            #pragma unroll
            for (int r = 0; r < 4; ++r) {
                int row_w = lg * 4 + r;
                int boff  = row_w * 256 + ((((ct * 16 + l16) * 2)) ^ ((row_w & 7) << 4));
                *(bf16*)(pbase_lds + boff) = __float2bfloat16(sc[ct][r]);
            }
        asm volatile("s_waitcnt lgkmcnt(0)" ::: "memory");

        short8 pa[4];
        #pragma unroll
        for (int kc = 0; kc < 4; ++kc)
            pa[kc] = *(const short8*)(pbase_lds + l16 * 256 +
                                      ((kc * 64 + lg * 16) ^ ((l16 & 7) << 4)));

        // ---- O += P V ----
        #pragma unroll
        for (int dt = 0; dt < 4; ++dt)
            #pragma unroll
            for (int kc = 0; kc < 4; ++kc)
                mfma_16x16x32(oacc[dt], pa[kc], vf[dt][kc]);
    }

    if (S == 1) {
        #pragma unroll
        for (int r = 0; r < 4; ++r) {
            float inv = 1.f / l[r];
            int qrow = row0g + lg * 4 + r;
            float* ob = out + ((size_t)b * NN + qrow) * DD;
            #pragma unroll
            for (int dt = 0; dt < 4; ++dt)
                ob[dt * 16 + l16] = oacc[dt][r] * inv;
        }
    } else {
        #pragma unroll
        for (int r = 0; r < 4; ++r) {
            int row = wave * 16 + lg * 4 + r;
            #pragma unroll
            for (int dt = 0; dt < 4; ++dt)
                partO[(size_t)idx * 4096 + row * 64 + dt * 16 + l16] = oacc[dt][r];
            if (l16 == 0) {
                partML[(size_t)idx * 128 + row]      = m[r];
                partML[(size_t)idx * 128 + 64 + row] = l[r];
            }
        }
    }
}

// ---------------- combine partials ----------------------------------------
__global__ __launch_bounds__(256) void combine_kernel(
    const float* __restrict__ partO, const float* __restrict__ partML,
    float* __restrict__ out, int S)
{
    const int blk = blockIdx.x;              // b*64 + qt
    const int qt  = blk & 63;
    const int tid = threadIdx.x;
    const int row = tid >> 2;
    const int c0  = (tid & 3) << 4;
    const int T   = (qt + 2) >> 1;
    const int len = (T + S - 1) / S;
    const int nse = (T + len - 1) / len;     // # nonempty splits

    float M = -INFINITY;
    for (int s = 0; s < nse; ++s)
        M = fmaxf(M, partML[((size_t)blk * S + s) * 128 + row]);

    float L = 0.f;
    f32x4 acc[4];
    #pragma unroll
    for (int j = 0; j < 4; ++j) acc[j] = (f32x4){0.f, 0.f, 0.f, 0.f};
    for (int s = 0; s < nse; ++s) {
        float e = __expf(partML[((size_t)blk * S + s) * 128 + row] - M);
        L += partML[((size_t)blk * S + s) * 128 + 64 + row] * e;
        const f32x4* po = (const f32x4*)(partO + ((size_t)blk * S + s) * 4096 + row * 64 + c0);
        #pragma unroll
        for (int j = 0; j < 4; ++j) acc[j] += po[j] * e;
    }
    float inv = 1.f / L;
    f32x4* ob = (f32x4*)(out + (size_t)blk * 4096 + row * 64 + c0);
    #pragma unroll
    for (int j = 0; j < 4; ++j) ob[j] = acc[j] * inv;
}

extern "C" void kernel_launch(void* const* d_in, const int* in_sizes, int n_in,
                              void* d_out, int out_size, void* d_ws, size_t ws_size,
                              hipStream_t stream) {
    const float* x  = (const float*)d_in[0];
    const float* Wq = (const float*)d_in[1];
    const float* Wk = (const float*)d_in[2];
    const float* Wv = (const float*)d_in[3];

    bf16* q  = (bf16*)d_ws;
    bf16* k  = q  + (size_t)BB * NN * DD;
    bf16* vT = k  + (size_t)BB * NN * DD;
    bf16* WT = vT + (size_t)BB * NN * DD;
    char* pbase = (char*)(WT + 3 * DD * DIN);
    size_t mis = (size_t)pbase & 15;
    if (mis) pbase += 16 - mis;

    int S = 8;
    while (S > 1) {
        size_t need = (size_t)(pbase - (char*)d_ws) +
                      (size_t)BB * 64 * S * (4096 + 128) * sizeof(float);
        if (need <= ws_size) break;
        S >>= 1;
    }
    float* partO  = (float*)pbase;
    float* partML = partO + (size_t)BB * 64 * S * 4096;

    convw_kernel<<<(3 * DD * DIN) / 256, 256, 0, stream>>>(Wq, Wk, Wv, WT);
    proj_kernel<<<BB * NN / 64, 512, 0, stream>>>(x, WT, q, k, vT);
    attn_split_kernel<<<BB * 64 * S, 256, 0, stream>>>(q, k, vT, partO, partML,
                                                       (float*)d_out, S);
    if (S > 1)
        combine_kernel<<<BB * 64, 256, 0, stream>>>(partO, partML, (float*)d_out, S);
}

// Round 6
// 130.892 us; speedup vs baseline: 1.2163x; 1.2163x over previous
//
#include <hip/hip_runtime.h>
#include <hip/hip_bf16.h>

#define BB 4
#define NN 4096
#define DIN 512
#define DD 64

typedef __attribute__((ext_vector_type(8))) short short8;
typedef __attribute__((ext_vector_type(4))) float f32x4;
typedef __attribute__((ext_vector_type(4))) unsigned short us4;
using bf16 = __hip_bfloat16;

__device__ inline void mfma_16x16x32(f32x4& d, short8 a, short8 b) {
    asm("v_mfma_f32_16x16x32_bf16 %0, %1, %2, %0" : "+v"(d) : "v"(a), "v"(b));
}

__device__ inline short8 load_cvt8(const float* __restrict__ src) {
    f32x4 f0 = *(const f32x4*)(src);
    f32x4 f1 = *(const f32x4*)(src + 4);
    bf16 t[8];
    #pragma unroll
    for (int j = 0; j < 4; ++j) t[j]     = __float2bfloat16(f0[j]);
    #pragma unroll
    for (int j = 0; j < 4; ++j) t[4 + j] = __float2bfloat16(f1[j]);
    return *(short8*)t;
}

// ---------------- W transpose+convert: WT[g][kk] = W_{g/64}[kk][g%64] -----
__global__ __launch_bounds__(256) void convw_kernel(
    const float* __restrict__ Wq, const float* __restrict__ Wk,
    const float* __restrict__ Wv, bf16* __restrict__ WT)
{
    int idx = blockIdx.x * 256 + threadIdx.x;   // 3*64*512 = 98304
    int w   = idx >> 15;
    int rem = idx & 32767;
    int n   = rem >> 9;
    int kk  = rem & 511;
    const float* W = (w == 0) ? Wq : (w == 1) ? Wk : Wv;
    WT[idx] = __float2bfloat16(W[kk * DD + n]);
}

// ---------------- MFMA projection, A direct from global -------------------
__global__ __launch_bounds__(512) void proj_kernel(
    const float* __restrict__ x, const bf16* __restrict__ WT,
    bf16* __restrict__ q, bf16* __restrict__ k, bf16* __restrict__ vT)
{
    const int tid   = threadIdx.x;
    const int row0  = blockIdx.x * 64;
    const int b     = row0 >> 12;
    const int nrow0 = row0 & 4095;
    const int lane  = tid & 63;
    const int l16   = lane & 15;
    const int lg    = lane >> 4;
    const int wave  = tid >> 6;
    const int rblk  = (wave >> 2) * 32;
    const int cbase = (wave & 3) * 48;

    f32x4 acc[2][3];
    #pragma unroll
    for (int rt = 0; rt < 2; ++rt)
        #pragma unroll
        for (int ct = 0; ct < 3; ++ct) acc[rt][ct] = (f32x4){0.f, 0.f, 0.f, 0.f};

    const float* xa = x  + (size_t)(row0 + rblk + l16) * DIN + lg * 8;
    const bf16*  wb = WT + (size_t)(cbase + l16) * DIN + lg * 8;

    #pragma unroll 4
    for (int ks = 0; ks < 16; ++ks) {
        short8 a0 = load_cvt8(xa + ks * 32);
        short8 a1 = load_cvt8(xa + 16 * DIN + ks * 32);
        short8 w0 = *(const short8*)(wb + ks * 32);
        short8 w1 = *(const short8*)(wb + 16 * DIN + ks * 32);
        short8 w2 = *(const short8*)(wb + 32 * DIN + ks * 32);
        mfma_16x16x32(acc[0][0], a0, w0);
        mfma_16x16x32(acc[0][1], a0, w1);
        mfma_16x16x32(acc[0][2], a0, w2);
        mfma_16x16x32(acc[1][0], a1, w0);
        mfma_16x16x32(acc[1][1], a1, w1);
        mfma_16x16x32(acc[1][2], a1, w2);
    }

    #pragma unroll
    for (int ct = 0; ct < 3; ++ct) {
        int g = cbase + ct * 16 + l16;
        int w = g >> 6;
        int n = g & 63;
        #pragma unroll
        for (int rt = 0; rt < 2; ++rt) {
            if (w == 2) {
                us4 pv;
                #pragma unroll
                for (int r = 0; r < 4; ++r) {
                    bf16 hv = __float2bfloat16(acc[rt][ct][r]);
                    pv[r] = *(unsigned short*)&hv;
                }
                int row = nrow0 + rblk + rt * 16 + lg * 4;
                *(us4*)(vT + ((size_t)b * DD + n) * NN + row) = pv;
            } else {
                bf16* dst = (w == 0) ? q : k;
                float sc  = (w == 0) ? 0.125f : 1.0f;
                #pragma unroll
                for (int r = 0; r < 4; ++r) {
                    int row = nrow0 + rblk + rt * 16 + lg * 4 + r;
                    dst[((size_t)b * NN + row) * DD + n] =
                        __float2bfloat16(acc[rt][ct][r] * sc);
                }
            }
        }
    }
}

// ---------------- split-KV flash attention, 128-key iterations ------------
// idx -> (b, qtRaw, s); qt = 63-qtRaw (heavy blocks dispatch first)
__global__ __launch_bounds__(256) void attn_split_kernel(
    const bf16* __restrict__ q, const bf16* __restrict__ k,
    const bf16* __restrict__ vT,
    float* __restrict__ partO, float* __restrict__ partML,
    float* __restrict__ out, int S)
{
    const int idx = blockIdx.x;
    const int s   = idx % S;
    const int qt  = 63 - ((idx / S) & 63);   // heavy-first remap
    const int b   = idx / (S * 64);
    const size_t sidx = ((size_t)b * 64 + qt) * S + s;   // canonical partial slot

    const int T   = (qt + 2) >> 1;          // # of 128-key blocks
    const int len = (T + S - 1) / S;
    const int t0  = s * len;
    const int t1  = (t0 + len < T) ? t0 + len : T;

    if (t0 >= t1) {                          // empty split: neutral partials
        const int tid = threadIdx.x;
        const int row = tid >> 2;
        const int c0  = (tid & 3) << 4;
        f32x4 z = (f32x4){0.f, 0.f, 0.f, 0.f};
        f32x4* po = (f32x4*)(partO + sidx * 4096 + row * 64 + c0);
        #pragma unroll
        for (int j = 0; j < 4; ++j) po[j] = z;
        if (tid < 64) {
            partML[sidx * 128 + tid]      = -INFINITY;
            partML[sidx * 128 + 64 + tid] = 0.f;
        }
        return;
    }

    const int wave = threadIdx.x >> 6;
    const int lane = threadIdx.x & 63;
    const int l16  = lane & 15;
    const int lg   = lane >> 4;

    __shared__ __align__(16) bf16 p_lds[4][16][128];   // 16 KB, XOR-swizzled
    char* pbase_lds = (char*)p_lds + wave * 4096;

    const int row0g = qt * 64 + wave * 16;   // wave's first q row (global)

    const bf16* qbase = q + ((size_t)b * NN + row0g + l16) * DD + lg * 8;
    short8 qfrag0 = *(const short8*)(qbase);
    short8 qfrag1 = *(const short8*)(qbase + 32);

    f32x4 oacc[4];
    #pragma unroll
    for (int dt = 0; dt < 4; ++dt) oacc[dt] = (f32x4){0.f, 0.f, 0.f, 0.f};
    float m[4], l[4];
    #pragma unroll
    for (int r = 0; r < 4; ++r) { m[r] = -INFINITY; l[r] = 0.f; }

    const bf16* kbase0 = k + ((size_t)b * NN + l16) * DD + lg * 8;
    const bf16* vbase0 = vT + ((size_t)b * DD + l16) * NN + lg * 8;

    // prefetch K for first tile
    short8 kf[8][2];
    {
        const bf16* kp = kbase0 + (size_t)t0 * 128 * DD;
        #pragma unroll
        for (int ct = 0; ct < 8; ++ct) {
            kf[ct][0] = *(const short8*)(kp + (size_t)ct * 16 * DD);
            kf[ct][1] = *(const short8*)(kp + (size_t)ct * 16 * DD + 32);
        }
    }

    for (int t = t0; t < t1; ++t) {
        // ---- S = Q K^T over 128 keys ----
        f32x4 sc[8];
        #pragma unroll
        for (int ct = 0; ct < 8; ++ct) sc[ct] = (f32x4){0.f, 0.f, 0.f, 0.f};
        #pragma unroll
        for (int ct = 0; ct < 8; ++ct) {
            mfma_16x16x32(sc[ct], qfrag0, kf[ct][0]);
            mfma_16x16x32(sc[ct], qfrag1, kf[ct][1]);
        }

        // ---- early-issue V loads for this tile ----
        const bf16* vbase = vbase0 + (size_t)t * 128;
        short8 vf[4][4];
        #pragma unroll
        for (int dt = 0; dt < 4; ++dt)
            #pragma unroll
            for (int kc = 0; kc < 4; ++kc)
                vf[dt][kc] = *(const short8*)(vbase + (size_t)dt * 16 * NN + kc * 32);

        // ---- prefetch K for next tile (covered by softmax+PV) ----
        if (t + 1 < t1) {
            const bf16* kp = kbase0 + (size_t)(t + 1) * 128 * DD;
            #pragma unroll
            for (int ct = 0; ct < 8; ++ct) {
                kf[ct][0] = *(const short8*)(kp + (size_t)ct * 16 * DD);
                kf[ct][1] = *(const short8*)(kp + (size_t)ct * 16 * DD + 32);
            }
        }

        // ---- causal mask (only when tile can touch the diagonal) ----
        if (t * 128 + 127 > row0g) {
            #pragma unroll
            for (int ct = 0; ct < 8; ++ct) {
                int gk = t * 128 + ct * 16 + l16;
                #pragma unroll
                for (int r = 0; r < 4; ++r)
                    if (gk > row0g + lg * 4 + r)
                        sc[ct][r] = -INFINITY;
            }
        }

        // ---- online softmax over 128 keys ----
        float mt[4];
        #pragma unroll
        for (int r = 0; r < 4; ++r) {
            float a = fmaxf(fmaxf(sc[0][r], sc[1][r]), fmaxf(sc[2][r], sc[3][r]));
            float c = fmaxf(fmaxf(sc[4][r], sc[5][r]), fmaxf(sc[6][r], sc[7][r]));
            mt[r] = fmaxf(a, c);
        }
        #pragma unroll
        for (int off = 1; off < 16; off <<= 1)
            #pragma unroll
            for (int r = 0; r < 4; ++r)
                mt[r] = fmaxf(mt[r], __shfl_xor(mt[r], off));

        float alpha[4];
        #pragma unroll
        for (int r = 0; r < 4; ++r) {
            float mn = fmaxf(m[r], mt[r]);
            alpha[r] = __expf(m[r] - mn);
            m[r] = mn;
        }

        float ls[4] = {0.f, 0.f, 0.f, 0.f};
        #pragma unroll
        for (int ct = 0; ct < 8; ++ct)
            #pragma unroll
            for (int r = 0; r < 4; ++r) {
                float p = __expf(sc[ct][r] - m[r]);
                sc[ct][r] = p;
                ls[r] += p;
            }
        #pragma unroll
        for (int off = 1; off < 16; off <<= 1)
            #pragma unroll
            for (int r = 0; r < 4; ++r)
                ls[r] += __shfl_xor(ls[r], off);
        #pragma unroll
        for (int r = 0; r < 4; ++r)
            l[r] = l[r] * alpha[r] + ls[r];

        #pragma unroll
        for (int dt = 0; dt < 4; ++dt)
            #pragma unroll
            for (int r = 0; r < 4; ++r)
                oacc[dt][r] *= alpha[r];

        // ---- P -> LDS (XOR-swizzled rows) ----
        #pragma unroll
        for (int ct = 0; ct < 8; ++ct)
            #pragma unroll
            for (int r = 0; r < 4; ++r) {
                int row_w = lg * 4 + r;
                int boff  = row_w * 256 + ((((ct * 16 + l16) * 2)) ^ ((row_w & 7) << 4));
                *(bf16*)(pbase_lds + boff) = __float2bfloat16(sc[ct][r]);
            }
        asm volatile("s_waitcnt lgkmcnt(0)" ::: "memory");

        short8 pa[4];
        #pragma unroll
        for (int kc = 0; kc < 4; ++kc)
            pa[kc] = *(const short8*)(pbase_lds + l16 * 256 +
                                      ((kc * 64 + lg * 16) ^ ((l16 & 7) << 4)));

        // ---- O += P V ----
        #pragma unroll
        for (int dt = 0; dt < 4; ++dt)
            #pragma unroll
            for (int kc = 0; kc < 4; ++kc)
                mfma_16x16x32(oacc[dt], pa[kc], vf[dt][kc]);
    }

    if (S == 1) {
        #pragma unroll
        for (int r = 0; r < 4; ++r) {
            float inv = 1.f / l[r];
            int qrow = row0g + lg * 4 + r;
            float* ob = out + ((size_t)b * NN + qrow) * DD;
            #pragma unroll
            for (int dt = 0; dt < 4; ++dt)
                ob[dt * 16 + l16] = oacc[dt][r] * inv;
        }
    } else {
        #pragma unroll
        for (int r = 0; r < 4; ++r) {
            int row = wave * 16 + lg * 4 + r;
            #pragma unroll
            for (int dt = 0; dt < 4; ++dt)
                partO[sidx * 4096 + row * 64 + dt * 16 + l16] = oacc[dt][r];
            if (l16 == 0) {
                partML[sidx * 128 + row]      = m[r];
                partML[sidx * 128 + 64 + row] = l[r];
            }
        }
    }
}

// ---------------- combine partials ----------------------------------------
__global__ __launch_bounds__(256) void combine_kernel(
    const float* __restrict__ partO, const float* __restrict__ partML,
    float* __restrict__ out, int S)
{
    const int blk = blockIdx.x;              // b*64 + qt
    const int qt  = blk & 63;
    const int tid = threadIdx.x;
    const int row = tid >> 2;
    const int c0  = (tid & 3) << 4;
    const int T   = (qt + 2) >> 1;
    const int len = (T + S - 1) / S;
    const int nse = (T + len - 1) / len;     // # nonempty splits

    float M = -INFINITY;
    for (int s = 0; s < nse; ++s)
        M = fmaxf(M, partML[((size_t)blk * S + s) * 128 + row]);

    float L = 0.f;
    f32x4 acc[4];
    #pragma unroll
    for (int j = 0; j < 4; ++j) acc[j] = (f32x4){0.f, 0.f, 0.f, 0.f};
    for (int s = 0; s < nse; ++s) {
        float e = __expf(partML[((size_t)blk * S + s) * 128 + row] - M);
        L += partML[((size_t)blk * S + s) * 128 + 64 + row] * e;
        const f32x4* po = (const f32x4*)(partO + ((size_t)blk * S + s) * 4096 + row * 64 + c0);
        #pragma unroll
        for (int j = 0; j < 4; ++j) acc[j] += po[j] * e;
    }
    float inv = 1.f / L;
    f32x4* ob = (f32x4*)(out + (size_t)blk * 4096 + row * 64 + c0);
    #pragma unroll
    for (int j = 0; j < 4; ++j) ob[j] = acc[j] * inv;
}

extern "C" void kernel_launch(void* const* d_in, const int* in_sizes, int n_in,
                              void* d_out, int out_size, void* d_ws, size_t ws_size,
                              hipStream_t stream) {
    const float* x  = (const float*)d_in[0];
    const float* Wq = (const float*)d_in[1];
    const float* Wk = (const float*)d_in[2];
    const float* Wv = (const float*)d_in[3];

    bf16* q  = (bf16*)d_ws;
    bf16* k  = q  + (size_t)BB * NN * DD;
    bf16* vT = k  + (size_t)BB * NN * DD;
    bf16* WT = vT + (size_t)BB * NN * DD;
    char* pbase = (char*)(WT + 3 * DD * DIN);
    size_t mis = (size_t)pbase & 15;
    if (mis) pbase += 16 - mis;

    int S = 8;
    while (S > 1) {
        size_t need = (size_t)(pbase - (char*)d_ws) +
                      (size_t)BB * 64 * S * (4096 + 128) * sizeof(float);
        if (need <= ws_size) break;
        S >>= 1;
    }
    float* partO  = (float*)pbase;
    float* partML = partO + (size_t)BB * 64 * S * 4096;

    convw_kernel<<<(3 * DD * DIN) / 256, 256, 0, stream>>>(Wq, Wk, Wv, WT);
    proj_kernel<<<BB * NN / 64, 512, 0, stream>>>(x, WT, q, k, vT);
    attn_split_kernel<<<BB * 64 * S, 256, 0, stream>>>(q, k, vT, partO, partML,
                                                       (float*)d_out, S);
    if (S > 1)
        combine_kernel<<<BB * 64, 256, 0, stream>>>(partO, partML, (float*)d_out, S);
}